// Round 14
// baseline (125.139 us; speedup 1.0000x reference)
//
#include <hip/hip_runtime.h>
#include <hip/hip_bf16.h>
#include <math.h>

#define C    32      // attention dim
#define QD   64      // x1 channels
#define VD   64      // output channels
#define BLK  512     // sliding window block length
#define HALF 256

typedef __attribute__((ext_vector_type(8))) short bf16x8;
typedef __attribute__((ext_vector_type(4))) float f32x4;

static __device__ inline unsigned short f2bf(float x) {
    union { float f; unsigned u; } v; v.f = x;
    unsigned r = v.u + 0x7FFFu + ((v.u >> 16) & 1u);   // RNE
    return (unsigned short)(r >> 16);
}

// pack 2 floats -> one dword holding 2 bf16 (low = a, high = b)
static __device__ inline unsigned pk2(float a, float b) {
    union { __hip_bfloat162 h; unsigned u; } x;
    x.h = __float22bfloat162_rn(make_float2(a, b));
    return x.u;
}

// ---------------- kernel 1: QKV projection via MFMA, W-frags amortized ----
// R13 config (124.0us, best-equal with R8). qkv post-mortem (R14): the
// subtraction-based "qkv=20-22us" included ~9us of inter-dispatch gaps
// (R3 direct measurement: 178.4 = 86 fills + 13 att + 70 qkv + ~9 gaps);
// real dispatch ~13-16us — why 5 qkv-internal theories all returned null.
// Parked. Failed theories (do not retry): R6 store coalescing; R9
// occupancy/hoisting; R10/R11 fusion into att (8.5x x1 amplification);
// R13 W-amortization (~null). Layouts for att_kernel:
//   qT bf16 (L,32) pre-scaled; kT bf16 (L,32);
//   v2 bf16 tiled: idx = ((l>>6)<<11) + (((l>>5)&1)<<10) + ch*32 + (l&31)
__global__ __launch_bounds__(256, 4) void qkv_proj(
    const float* __restrict__ x1,
    const float* __restrict__ Wq, const float* __restrict__ bq,
    const float* __restrict__ Wk, const float* __restrict__ bk,
    const float* __restrict__ Wv, const float* __restrict__ bv,
    unsigned short* __restrict__ qT, unsigned short* __restrict__ kT,
    unsigned short* __restrict__ v2, int L)
{
    __shared__ uint4 lq[256], lk[256], lv[256];   // 3 x 4KB

    const int lane = threadIdx.x & 63;
    const int wv   = threadIdx.x >> 6;
    const int lo   = lane & 15;
    const int quad = lane >> 4;
    const int ll   = wv * 16 + lo;          // l offset within a 64-l block

    // ---- W A-frags ONCE per wave (q-scale folded into Wq) ----
    bf16x8 WF[3][2][2];   // [kind][otile][kchunk] — static after unroll
    #pragma unroll
    for (int kind = 0; kind < 3; ++kind) {
        const float* __restrict__ Wp = (kind == 0) ? Wq : ((kind == 1) ? Wk : Wv);
        const float sc = (kind == 0) ? 0.17677669529663689f : 1.0f;
        #pragma unroll
        for (int ot = 0; ot < 2; ++ot) {
            #pragma unroll
            for (int kc = 0; kc < 2; ++kc) {
                const float* wp = Wp + (size_t)(ot * 16 + lo) * QD + kc * 32 + quad * 8;
                const float4 w0 = *(const float4*)wp;
                const float4 w1 = *(const float4*)(wp + 4);
                union { unsigned u[4]; bf16x8 v; } t;
                t.u[0] = pk2(w0.x * sc, w0.y * sc);
                t.u[1] = pk2(w0.z * sc, w0.w * sc);
                t.u[2] = pk2(w1.x * sc, w1.y * sc);
                t.u[3] = pk2(w1.z * sc, w1.w * sc);
                WF[kind][ot][kc] = t.v;
            }
        }
    }

    // ---- 2 passes of 64 timesteps, reusing WF ----
    #pragma unroll
    for (int p = 0; p < 2; ++p) {
        const int tile = blockIdx.x * 8 + p * 4 + wv;   // wave's 16-l tile
        const int l    = tile * 16 + lo;

        float xv[16];
        #pragma unroll
        for (int kc = 0; kc < 2; ++kc)
            #pragma unroll
            for (int j = 0; j < 8; ++j)
                xv[kc * 8 + j] = x1[(size_t)(kc * 32 + quad * 8 + j) * L + l];

        bf16x8 B[2];
        #pragma unroll
        for (int kc = 0; kc < 2; ++kc) {
            union { unsigned u[4]; bf16x8 v; } bb;
            #pragma unroll
            for (int pp = 0; pp < 4; ++pp)
                bb.u[pp] = pk2(xv[kc * 8 + 2 * pp], xv[kc * 8 + 2 * pp + 1]);
            B[kc] = bb.v;
        }

        const f32x4 zero = {0.f, 0.f, 0.f, 0.f};
        f32x4 acc[3][2];
        #pragma unroll
        for (int kind = 0; kind < 3; ++kind)
            #pragma unroll
            for (int ot = 0; ot < 2; ++ot) {
                f32x4 a = __builtin_amdgcn_mfma_f32_16x16x32_bf16(WF[kind][ot][0], B[0], zero, 0, 0, 0);
                acc[kind][ot] = __builtin_amdgcn_mfma_f32_16x16x32_bf16(WF[kind][ot][1], B[1], a, 0, 0, 0);
            }

        #pragma unroll
        for (int kind = 0; kind < 2; ++kind) {
            const float* __restrict__ bp = (kind == 0) ? bq : bk;
            const float sc = (kind == 0) ? 0.17677669529663689f : 1.0f;
            unsigned* __restrict__ ld = (unsigned*)((kind == 0) ? lq : lk);
            #pragma unroll
            for (int ot = 0; ot < 2; ++ot) {
                const float4 b4 = *(const float4*)(bp + ot * 16 + quad * 4);
                const float r0 = acc[kind][ot][0] + b4.x * sc;
                const float r1 = acc[kind][ot][1] + b4.y * sc;
                const float r2 = acc[kind][ot][2] + b4.z * sc;
                const float r3 = acc[kind][ot][3] + b4.w * sc;
                ld[ll * 16 + ot * 8 + quad * 2 + 0] = pk2(r0, r1);
                ld[ll * 16 + ot * 8 + quad * 2 + 1] = pk2(r2, r3);
            }
        }
        {
            unsigned short* __restrict__ lvs = (unsigned short*)lv;
            const int vb = ((ll >> 5) << 10) + (ll & 31);
            #pragma unroll
            for (int ot = 0; ot < 2; ++ot) {
                const float4 b4 = *(const float4*)(bv + ot * 16 + quad * 4);
                const float* bp4 = (const float*)&b4;
                #pragma unroll
                for (int r = 0; r < 4; ++r)
                    lvs[vb + (ot * 16 + quad * 4 + r) * 32] = f2bf(acc[2][ot][r] + bp4[r]);
            }
        }

        __syncthreads();

        const int t = threadIdx.x;
        const size_t blk16 = ((size_t)blockIdx.x * 2 + p) * 256;
        ((uint4*)qT)[blk16 + t] = lq[t];
        ((uint4*)kT)[blk16 + t] = lk[t];
        ((uint4*)v2)[blk16 + t] = lv[t];

        if (p == 0) __syncthreads();   // protect LDS reuse by pass 1
    }
}

// ---------------- kernel 2: MFMA flash attention, LDS-shared window ------
// R14: extend R8's verified mechanism (window sharing) 64->128 queries/wg:
// 8 waves, 512 threads. Per chunk, threads 0-255 stage K, 256-511 stage V
// (1 uint4/thread, was 2); K/V traffic halves again (~57->~30MB); barriers
// per query halve. Read paths/swizzle/causal/epilogue byte-identical per
// wave (V swizzle row g*32 ≡ 0 mod 4 -> rdX unchanged). Grid L/128 = 512
// wgs = 2/CU all-resident. Pins: no per-wave register pipeline (R7); no
// projection fusion (R10/R11).
__global__ __launch_bounds__(512, 4) void att_kernel(
    const unsigned short* __restrict__ qT,
    const unsigned short* __restrict__ kT,
    const unsigned short* __restrict__ v2,
    const float* __restrict__ mask,
    const float* __restrict__ Wo, const float* __restrict__ bo,
    float* __restrict__ out, int L)
{
    __shared__ unsigned short sK[2][2048];   // [buf][64 keys][32 ch]
    __shared__ unsigned short sV[2][2048];   // [buf][2][32 ch][32 keys]

    const int tid  = threadIdx.x;
    const int lane = tid & 63;
    const int wvi  = tid >> 6;          // wave 0..7 -> tile s = sub*8+wvi
    const int lo   = lane & 15;
    const int quad = lane >> 4;

    // LPT + XCD affinity: id = (3-sub)*128 + w -> long wgs first, id%8==w%8
    const int id  = blockIdx.x;
    const int w   = id & 127;           // 512-block index
    const int sub = 3 - (id >> 7);      // 128-query group within block
    const int s   = sub * 8 + wvi;
    const int wq0 = w * BLK + s * 16;

    const int kstart = max(0, w * BLK - HALF);
    const int nwv  = ((wq0 + 15 - kstart) >> 6) + 1;                          // my chunks
    const int nmax = ((w * BLK + (sub * 8 + 7) * 16 + 15 - kstart) >> 6) + 1; // wg chunks
    const int myq  = wq0 + lo;

    // Q B-frag: B[k=c][n=q]
    const bf16x8 qB = *(const bf16x8*)(qT + (size_t)myq * C + quad * 8);

    const f32x4 zero = {0.f, 0.f, 0.f, 0.f};
    f32x4 O0 = zero, O1 = zero;
    float psum = 0.f;

    const int qsl = lo + 16 * ((quad & 1) << 1);

    // staging split: threads 0-255 stage K, 256-511 stage V (1 uint4 each)
    const int st    = tid & 255;
    const bool isK  = tid < 256;
    const int wrOff = (st * 16) ^ (((st >> 3) & 3) << 4);        // ds_write_b128
    const int rdX   = (quad << 4) ^ (((lo >> 1) & 3) << 4);      // read column

    // ---- prologue: stage chunk 0 ----
    {
        const uint4 g0 = isK
            ? ((const uint4*)(kT + (size_t)kstart * C))[st]
            : ((const uint4*)(v2 + ((size_t)(kstart >> 6) << 11)))[st];
        *(uint4*)((char*)(isK ? sK[0] : sV[0]) + wrOff) = g0;
    }
    __syncthreads();

    for (int j = 0; j < nmax; ++j) {
        const int kb  = kstart + (j << 6);
        const int cur = j & 1;
        const bool more = (j + 1) < nmax;

        // issue next chunk's global load EARLY (latency hidden by compute)
        uint4 gn;
        if (more) {
            const int kb1 = kb + 64;
            gn = isK
                ? ((const uint4*)(kT + (size_t)kb1 * C))[st]
                : ((const uint4*)(v2 + ((size_t)(kb1 >> 6) << 11)))[st];
        }

        if (j < nwv) {
            // ---- S = K.Q^T from LDS ----
            f32x4 S[4];
            float4 fm4[4];
            const char* kbuf = (const char*)sK[cur];
            #pragma unroll
            for (int t = 0; t < 4; ++t) {
                const bf16x8 kA = *(const bf16x8*)(kbuf + ((t * 16 + lo) * 64 + rdX));
                S[t] = __builtin_amdgcn_mfma_f32_16x16x32_bf16(kA, qB, zero, 0, 0, 0);
                fm4[t] = *(const float4*)(mask + kb + t * 16 + quad * 4);
            }

            unsigned wp[4][2];
            if (j == nwv - 1) {
                // causal chunk
                #pragma unroll
                for (int t = 0; t < 4; ++t) {
                    const float* fmp = (const float*)&fm4[t];
                    float p[4];
                    #pragma unroll
                    for (int r = 0; r < 4; ++r) {
                        const int key = kb + t * 16 + quad * 4 + r;
                        const float pd = (key <= myq) ? __expf(S[t][r]) * (fmp[r] + 1e-9f) : 0.f;
                        psum += pd;
                        p[r] = pd * fmp[r];
                    }
                    wp[t][0] = pk2(p[0], p[1]);
                    wp[t][1] = pk2(p[2], p[3]);
                }
            } else {
                #pragma unroll
                for (int t = 0; t < 4; ++t) {
                    const float* fmp = (const float*)&fm4[t];
                    float p[4];
                    #pragma unroll
                    for (int r = 0; r < 4; ++r) {
                        const float pd = __expf(S[t][r]) * (fmp[r] + 1e-9f);
                        psum += pd;
                        p[r] = pd * fmp[r];
                    }
                    wp[t][0] = pk2(p[0], p[1]);
                    wp[t][1] = pk2(p[2], p[3]);
                }
            }

            // ---- PV from LDS ----
            const char* vbuf = (const char*)sV[cur];
            #pragma unroll
            for (int g = 0; g < 2; ++g) {
                union { int i[4]; bf16x8 v; } pb;
                #pragma unroll
                for (int i = 0; i < 4; ++i) {
                    const int src = qsl + 16 * (i >> 1);
                    const int v0 = __shfl((int)wp[2 * g][i & 1], src);
                    const int v1 = __shfl((int)wp[2 * g + 1][i & 1], src);
                    pb.i[i] = (quad < 2) ? v0 : v1;
                }
                const bf16x8 vA0 = *(const bf16x8*)(vbuf + (g * 2048 + lo * 64 + rdX));
                const bf16x8 vA1 = *(const bf16x8*)(vbuf + (g * 2048 + (16 + lo) * 64 + rdX));
                O0 = __builtin_amdgcn_mfma_f32_16x16x32_bf16(vA0, pb.v, O0, 0, 0, 0);
                O1 = __builtin_amdgcn_mfma_f32_16x16x32_bf16(vA1, pb.v, O1, 0, 0, 0);
            }
        }

        // write next chunk into the other buffer, then one barrier
        if (more)
            *(uint4*)((char*)(isK ? sK[cur ^ 1] : sV[cur ^ 1]) + wrOff) = gn;
        __syncthreads();
    }

    // ---- denominator across quads for each query col ----
    float dsum = psum;
    dsum += __shfl_xor(dsum, 16);
    dsum += __shfl_xor(dsum, 32);
    const float inv = 1.f / dsum;

    // ---- epilogue: T = relu(O^T*inv) -> B-layout via quad-permute ----
    unsigned tw[2][2];
    tw[0][0] = pk2(fmaxf(O0[0] * inv, 0.f), fmaxf(O0[1] * inv, 0.f));
    tw[0][1] = pk2(fmaxf(O0[2] * inv, 0.f), fmaxf(O0[3] * inv, 0.f));
    tw[1][0] = pk2(fmaxf(O1[0] * inv, 0.f), fmaxf(O1[1] * inv, 0.f));
    tw[1][1] = pk2(fmaxf(O1[2] * inv, 0.f), fmaxf(O1[3] * inv, 0.f));

    union { int i[4]; bf16x8 v; } tb;
    #pragma unroll
    for (int i = 0; i < 4; ++i) {
        const int src = qsl + 16 * (i >> 1);
        const int v0 = __shfl((int)tw[0][i & 1], src);
        const int v1 = __shfl((int)tw[1][i & 1], src);
        tb.i[i] = (quad < 2) ? v0 : v1;
    }

    const float mk = mask[myq];
    #pragma unroll
    for (int t = 0; t < 4; ++t) {
        float wtmp[8];
        *(float4*)&wtmp[0] = *(const float4*)(Wo + (size_t)(t * 16 + lo) * C + quad * 8);
        *(float4*)&wtmp[4] = *(const float4*)(Wo + (size_t)(t * 16 + lo) * C + quad * 8 + 4);
        union { unsigned u[4]; bf16x8 v; } wo;
        #pragma unroll
        for (int i = 0; i < 4; ++i) wo.u[i] = pk2(wtmp[2 * i], wtmp[2 * i + 1]);
        const f32x4 R = __builtin_amdgcn_mfma_f32_16x16x32_bf16(wo.v, tb.v, zero, 0, 0, 0);
        const float4 bo4 = *(const float4*)(bo + t * 16 + quad * 4);
        const float* bop = (const float*)&bo4;
        #pragma unroll
        for (int r = 0; r < 4; ++r)
            out[(size_t)(t * 16 + quad * 4 + r) * L + myq] = (R[r] + bop[r]) * mk;
    }
}

extern "C" void kernel_launch(void* const* d_in, const int* in_sizes, int n_in,
                              void* d_out, int out_size, void* d_ws, size_t ws_size,
                              hipStream_t stream)
{
    const float* x1   = (const float*)d_in[0];
    // d_in[1] = x2 : unused (encoder stage)
    const float* mask = (const float*)d_in[2];
    const float* Wq   = (const float*)d_in[3];
    const float* bq   = (const float*)d_in[4];
    const float* Wk   = (const float*)d_in[5];
    const float* bk   = (const float*)d_in[6];
    const float* Wv   = (const float*)d_in[7];
    const float* bv   = (const float*)d_in[8];
    const float* Wo   = (const float*)d_in[9];
    const float* bo   = (const float*)d_in[10];
    float* out = (float*)d_out;

    const int L = in_sizes[0] / QD;                  // 65536
    unsigned short* qT = (unsigned short*)d_ws;      // L*32 bf16
    unsigned short* kT = qT + (size_t)L * C;         // L*32 bf16
    unsigned short* v2 = kT + (size_t)L * C;         // L*32 bf16 (tiled)

    // MFMA qkv: 128 timesteps per wg (2 passes x 64) -> L/128 = 512 wgs
    hipLaunchKernelGGL(qkv_proj, dim3(L / 128), dim3(256), 0, stream,
                       x1, Wq, bq, Wk, bk, Wv, bv, qT, kT, v2, L);

    // one wg per 128-query group: L/128 = 512 wgs (8 waves, shared window)
    hipLaunchKernelGGL(att_kernel, dim3(L / 128), dim3(512), 0, stream,
                       qT, kT, v2, mask, Wo, bo, out, L);
}